// Round 19
// baseline (527.248 us; speedup 1.0000x reference)
//
#include <hip/hip_runtime.h>
#include <hip/hip_bf16.h>
#include <stdint.h>

// Problem constants
#define L_   1280
#define B_   32
#define C_   256
#define H_   5
#define D_   256
#define BC_  8192            // B_*C_
#define EPSV 1e-5f

typedef __attribute__((ext_vector_type(8))) short bf16x8;   // 8 bf16 (4 VGPRs)
typedef __attribute__((ext_vector_type(4))) float f32x4;    // 4 fp32 acc
typedef __hip_bfloat16 bf16;

__device__ __forceinline__ bf16 f2bf(float v) { return __float2bfloat16(v); }
__device__ __forceinline__ float bf2f(bf16 v) { return __bfloat162float(v); }

// async global->LDS, 16B per lane; LDS dest is wave-uniform base + lane*16
#define GLDS16(gptr, lptr)                                                        \
    __builtin_amdgcn_global_load_lds(                                             \
        (const __attribute__((address_space(1))) void*)(gptr),                    \
        (__attribute__((address_space(3))) void*)(lptr), 16, 0, 0)

// ---------------------------------------------------------------------------
// Weight prep: fp32 [K,N] -> bf16 [N,K] (transposed) for 7 LxL matrices
// ---------------------------------------------------------------------------
struct WtArgs { const float* src[7]; bf16* dst[7]; };

__global__ __launch_bounds__(256) void transpose7(WtArgs a) {
    const int mat = blockIdx.z;
    const float* src = a.src[mat];
    bf16* dst = a.dst[mat];
    __shared__ float tile[32][33];
    const int bx = blockIdx.x * 32;   // n base
    const int by = blockIdx.y * 32;   // k base
    const int tx = threadIdx.x, ty = threadIdx.y;
    #pragma unroll
    for (int r = ty; r < 32; r += 8)
        tile[r][tx] = src[(size_t)(by + r) * L_ + bx + tx];
    __syncthreads();
    #pragma unroll
    for (int r = ty; r < 32; r += 8)
        dst[(size_t)(bx + r) * L_ + by + tx] = f2bf(tile[tx][r]);
}

// conv weight pack: conv_w[co][ci][t] -> WT[co][t*256+ci]  (K=768 fused layout)
// plus BN scale/bias
__global__ __launch_bounds__(256) void prep_conv(const float* cw, const float* g, const float* b,
                                                 const float* m, const float* v,
                                                 bf16* WT, float* sc, float* bi) {
    const int i = blockIdx.x * 256 + threadIdx.x;
    if (i < 3 * 256 * 256) {
        const int co = i / 768;
        const int r = i - co * 768;
        const int t = r >> 8, ci = r & 255;
        WT[i] = f2bf(cw[(co * 256 + ci) * 3 + t]);
    }
    if (i < 256) {
        const float s = g[i] * rsqrtf(v[i] + EPSV);
        sc[i] = s;
        bi[i] = b[i] - m[i] * s;
    }
}

// ---------------------------------------------------------------------------
// Rank kernel (bucket-histogram; eq-before term dropped, < 2e-5 effect)
// ---------------------------------------------------------------------------
__global__ __launch_bounds__(256) void rank_kernel(const float* __restrict__ x, bf16* __restrict__ R) {
    __shared__ float vals[L_];
    __shared__ float sv[L_];
    __shared__ int hist[256];
    __shared__ int pfx[256];
    __shared__ int cur[256];
    const int row = blockIdx.x, tid = threadIdx.x;
    const float* src = x + (size_t)row * L_;
    for (int i = tid; i < L_; i += 256) vals[i] = src[i];
    hist[tid] = 0;
    __syncthreads();
    float myv[5]; int myb[5];
    #pragma unroll
    for (int ii = 0; ii < 5; ii++) {
        const float v = vals[tid + ii * 256];
        int bk = (int)((4.0f - v) * 32.0f);
        bk = bk < 0 ? 0 : (bk > 255 ? 255 : bk);
        myv[ii] = v; myb[ii] = bk;
        atomicAdd(&hist[bk], 1);
    }
    __syncthreads();
    pfx[tid] = hist[tid];
    __syncthreads();
    for (int off = 1; off < 256; off <<= 1) {
        int t = (tid >= off) ? pfx[tid - off] : 0;
        __syncthreads();
        pfx[tid] += t;
        __syncthreads();
    }
    cur[tid] = pfx[tid] - hist[tid];
    __syncthreads();
    #pragma unroll
    for (int ii = 0; ii < 5; ii++) {
        const int pos = atomicAdd(&cur[myb[ii]], 1);
        sv[pos] = myv[ii];
    }
    __syncthreads();
    #pragma unroll
    for (int ii = 0; ii < 5; ii++) {
        const int bk = myb[ii]; const float v = myv[ii];
        const int s = pfx[bk] - hist[bk], e = pfx[bk];
        int cg = s;
        for (int p = s; p < e; p++) cg += (sv[p] > v) ? 1 : 0;
        R[(size_t)row * L_ + tid + ii * 256] = f2bf((float)(L_ - cg) * (1.0f / L_));
    }
}

// ---------------------------------------------------------------------------
// LayerNorm over last dim (1280), bf16 in -> bf16 out
// ---------------------------------------------------------------------------
__global__ __launch_bounds__(256) void ln_kernel(const bf16* __restrict__ in,
                                                 const float* __restrict__ g,
                                                 const float* __restrict__ b,
                                                 bf16* __restrict__ out) {
    const int row = blockIdx.x, tid = threadIdx.x;
    const bf16* src = in + (size_t)row * L_;
    uint2 ra = ((const uint2*)src)[tid];
    bf16 a4[4]; *(uint2*)a4 = ra;
    const float a0 = bf2f(a4[0]), a1 = bf2f(a4[1]), a2 = bf2f(a4[2]), a3 = bf2f(a4[3]);
    float s = a0 + a1 + a2 + a3;
    float ss = a0 * a0 + a1 * a1 + a2 * a2 + a3 * a3;
    float b0 = 0, b1 = 0, b2 = 0, b3 = 0;
    if (tid < 64) {
        uint2 rb = ((const uint2*)src)[256 + tid];
        bf16 b4[4]; *(uint2*)b4 = rb;
        b0 = bf2f(b4[0]); b1 = bf2f(b4[1]); b2 = bf2f(b4[2]); b3 = bf2f(b4[3]);
        s += b0 + b1 + b2 + b3;
        ss += b0 * b0 + b1 * b1 + b2 * b2 + b3 * b3;
    }
    #pragma unroll
    for (int off = 32; off > 0; off >>= 1) {
        s += __shfl_down(s, off, 64);
        ss += __shfl_down(ss, off, 64);
    }
    __shared__ float rs[4], rss[4];
    __shared__ float mean_s, rstd_s;
    if ((tid & 63) == 0) { rs[tid >> 6] = s; rss[tid >> 6] = ss; }
    __syncthreads();
    if (tid == 0) {
        const float S = rs[0] + rs[1] + rs[2] + rs[3];
        const float SS = rss[0] + rss[1] + rss[2] + rss[3];
        const float m = S * (1.0f / L_);
        const float var = SS * (1.0f / L_) - m * m;
        mean_s = m; rstd_s = rsqrtf(var + EPSV);
    }
    __syncthreads();
    const float m = mean_s, r = rstd_s;
    {
        const int c = tid * 4;
        bf16 t4[4];
        t4[0] = f2bf((a0 - m) * r * g[c + 0] + b[c + 0]);
        t4[1] = f2bf((a1 - m) * r * g[c + 1] + b[c + 1]);
        t4[2] = f2bf((a2 - m) * r * g[c + 2] + b[c + 2]);
        t4[3] = f2bf((a3 - m) * r * g[c + 3] + b[c + 3]);
        *(uint2*)(out + (size_t)row * L_ + c) = *(uint2*)t4;
    }
    if (tid < 64) {
        const int c = 1024 + tid * 4;
        bf16 t4[4];
        t4[0] = f2bf((b0 - m) * r * g[c + 0] + b[c + 0]);
        t4[1] = f2bf((b1 - m) * r * g[c + 1] + b[c + 1]);
        t4[2] = f2bf((b2 - m) * r * g[c + 2] + b[c + 2]);
        t4[3] = f2bf((b3 - m) * r * g[c + 3] + b[c + 3]);
        *(uint2*)(out + (size_t)row * L_ + c) = *(uint2*)t4;
    }
}

// zero the two pad rows of h2Tpad [B][1282][256]
__global__ __launch_bounds__(256) void zero_pads(bf16* h2T) {
    const int i = blockIdx.x * 256 + threadIdx.x;   // 32*2*256 = 16384
    const int b = i >> 9;
    const int which = (i >> 8) & 1;
    const int ci = i & 255;
    const long row = which ? 1281 : 0;
    h2T[(long)b * (1282 * 256) + row * 256 + ci] = f2bf(0.0f);
}

// ---------------------------------------------------------------------------
// Fused S=QK^T + row-softmax -> P (bf16).  One block per (b,h,qtile128).
// (R18 kernel, unchanged — correct and cost-neutral, keeps fp32 logits.)
// ---------------------------------------------------------------------------
__global__ __launch_bounds__(256) void attn_sfuse(const bf16* __restrict__ Qb,
                                                  const bf16* __restrict__ Kb,
                                                  bf16* __restrict__ P) {
    const int z = blockIdx.z;                 // b*H + h
    const int b_ = z / H_, h_ = z % H_;
    const int row0 = blockIdx.x * 128;

    __shared__ __align__(16) bf16 shm[24576];

    const int tid = threadIdx.x;
    const int l = tid & 63, w = tid >> 6;
    const int wr = w >> 1, wc = w & 1;        // wave: rows wr*64, cols wc*128

    f32x4 acc[4][8];
    #pragma unroll
    for (int m = 0; m < 4; m++)
        #pragma unroll
        for (int n = 0; n < 8; n++)
            acc[m][n] = (f32x4){0.f, 0.f, 0.f, 0.f};

    const bf16* baseQ = Qb + (long)b_ * C_ * L_ + h_ * 256;
    const bf16* baseK = Kb + (long)b_ * C_ * L_ + h_ * 256;
    const bf16* gA = baseQ + (long)(row0 + w * 16 + (l >> 2)) * L_ + (l & 3) * 8;
    const bf16* gB = baseK + (long)(w * 16 + (l >> 2)) * L_ + (l & 3) * 8;

    auto STAGE = [&](int buf) {               // 6 loads/lane
        bf16* lA = shm + buf * 4096;
        bf16* lB = shm + 8192 + buf * 8192;
        GLDS16(gA,              lA + w * 512);
        GLDS16(gA + 64 * L_,    lA + 2048 + w * 512);
        #pragma unroll
        for (int c = 0; c < 4; c++)
            GLDS16(gB + (long)c * 64 * L_, lB + c * 2048 + w * 512);
        gA += 32; gB += 32;
    };
    auto COMPUTE = [&](int buf) {
        const bf16* lA = shm + buf * 4096;
        const bf16* lB = shm + 8192 + buf * 8192;
        bf16x8 aF[4], bF[8];
        #pragma unroll
        for (int n = 0; n < 8; n++)
            bF[n] = *(const bf16x8*)(lB + (wc * 128 + n * 16 + (l & 15)) * 32 + (l >> 4) * 8);
        #pragma unroll
        for (int m = 0; m < 4; m++)
            aF[m] = *(const bf16x8*)(lA + (wr * 64 + m * 16 + (l & 15)) * 32 + (l >> 4) * 8);
        #pragma unroll
        for (int m = 0; m < 4; m++)
            #pragma unroll
            for (int n = 0; n < 8; n++)
                acc[m][n] = __builtin_amdgcn_mfma_f32_16x16x32_bf16(aF[m], bF[n], acc[m][n], 0, 0, 0);
    };

    STAGE(0);
    int cur = 0;
    for (int t = 0; t < 7; ++t) {
        STAGE(cur ^ 1);
        asm volatile("s_waitcnt vmcnt(6)" ::: "memory");
        __builtin_amdgcn_sched_barrier(0);
        __builtin_amdgcn_s_barrier();
        COMPUTE(cur);
        __builtin_amdgcn_sched_barrier(0);
        __builtin_amdgcn_s_barrier();
        cur ^= 1;
    }
    asm volatile("s_waitcnt vmcnt(0)" ::: "memory");
    __builtin_amdgcn_sched_barrier(0);
    __builtin_amdgcn_s_barrier();
    COMPUTE(cur);

    // ---- row softmax ----
    float* red = (float*)shm;                 // [2][128], reused after barrier
    __syncthreads();                          // pipeline LDS reads complete
    const int lr = (l >> 4) * 4;              // local row base within 16-frag
    float rmax[4][4], rsum[4][4];
    #pragma unroll
    for (int m = 0; m < 4; m++)
        #pragma unroll
        for (int j = 0; j < 4; j++) {
            float v = acc[m][0][j];
            #pragma unroll
            for (int n = 1; n < 8; n++) v = fmaxf(v, acc[m][n][j]);
            #pragma unroll
            for (int mask = 1; mask < 16; mask <<= 1)
                v = fmaxf(v, __shfl_xor(v, mask, 64));
            rmax[m][j] = v;
        }
    if ((l & 15) == 0) {
        #pragma unroll
        for (int m = 0; m < 4; m++)
            #pragma unroll
            for (int j = 0; j < 4; j++)
                red[wc * 128 + wr * 64 + m * 16 + lr + j] = rmax[m][j];
    }
    __syncthreads();
    #pragma unroll
    for (int m = 0; m < 4; m++)
        #pragma unroll
        for (int j = 0; j < 4; j++)
            rmax[m][j] = fmaxf(rmax[m][j], red[(wc ^ 1) * 128 + wr * 64 + m * 16 + lr + j]);
    __syncthreads();                          // before red reuse for sums
    #pragma unroll
    for (int m = 0; m < 4; m++)
        #pragma unroll
        for (int j = 0; j < 4; j++) {
            float s = 0.f;
            #pragma unroll
            for (int n = 0; n < 8; n++) {
                const float e = expf(acc[m][n][j] - rmax[m][j]);
                acc[m][n][j] = e;
                s += e;
            }
            #pragma unroll
            for (int mask = 1; mask < 16; mask <<= 1)
                s += __shfl_xor(s, mask, 64);
            rsum[m][j] = s;
        }
    if ((l & 15) == 0) {
        #pragma unroll
        for (int m = 0; m < 4; m++)
            #pragma unroll
            for (int j = 0; j < 4; j++)
                red[wc * 128 + wr * 64 + m * 16 + lr + j] = rsum[m][j];
    }
    __syncthreads();
    #pragma unroll
    for (int m = 0; m < 4; m++)
        #pragma unroll
        for (int j = 0; j < 4; j++)
            rsum[m][j] += red[(wc ^ 1) * 128 + wr * 64 + m * 16 + lr + j];

    // ---- store P ----
    bf16* dstP = P + (long)z * 65536;
    #pragma unroll
    for (int m = 0; m < 4; m++)
        #pragma unroll
        for (int j = 0; j < 4; j++) {
            const int grow = row0 + wr * 64 + m * 16 + lr + j;
            const float rinv = 1.0f / rsum[m][j];
            #pragma unroll
            for (int n = 0; n < 8; n++) {
                const int gcol = wc * 128 + n * 16 + (l & 15);
                dstP[(long)grow * 256 + gcol] = f2bf(acc[m][n][j] * rinv);
            }
        }
}

// ---------------------------------------------------------------------------
// Generic batched GEMM: templated BM (128/256) x 128 cols, BK=32, 4 waves 2x2,
// and NBUF (2 or 3). NBUF=3: one-barrier 2-phase interleaved loop (R17).
// NBUF=2: two-barrier counted-vmcnt loop (R9-proven) — halves LDS to 48KB so
// BM=256 fits 3 blocks/CU (QKV occupancy was LDS-capped at 2).
// XCD chunking with row-fastest order inside each chunk (B-tile L2 reuse).
// ---------------------------------------------------------------------------
struct GemmP {
    const bf16* A;  long lda, sA1, sA2;
    const bf16* Bt; long ldb, sB1, sB2;
    int zmod;
    int K;
    float* outF; bf16* outB; bf16* outB2; bf16* outB3; long ldc, sC1, sC2;
    const float* bias; const float* bias2; const float* bias3;
    const float* res; const bf16* resB; long ldres, sR1, sR2;
    const float* rowscale; const float* rowbias;
    float scale;
};

constexpr int E_NODE = 0;
constexpr int E_HRES = 1;
constexpr int E_BF16 = 5;
constexpr int E_GELU = 6;
constexpr int E_FFN2T = 7;
constexpr int E_CONVBNR = 8;
constexpr int E_QKV = 9;

template <int EPI, int BM, int NBUF>
__global__ __launch_bounds__(256) void gemm_bt(GemmP p) {
    constexpr int MREP  = BM / 32;
    constexpr int HREP  = MREP / 2;
    constexpr int WM    = BM / 2;
    constexpr int ABUF  = BM * 32;
    constexpr int BBASE = NBUF * ABUF;

    const int nwg  = gridDim.x * gridDim.y * gridDim.z;
    const int orig = (blockIdx.z * gridDim.y + blockIdx.y) * gridDim.x + blockIdx.x;
    int bx, rowg;
    if ((nwg & 7) == 0) {
        const int chunk = nwg >> 3;
        const int xcd = orig & 7, pos = orig >> 3;
        const int rpc = chunk / gridDim.x;
        if (rpc * gridDim.x == chunk) {
            bx   = pos / rpc;
            rowg = xcd * rpc + (pos - bx * rpc);
        } else {
            const int wgid = xcd * chunk + pos;
            bx = wgid % gridDim.x; rowg = wgid / gridDim.x;
        }
    } else {
        bx = blockIdx.x; rowg = blockIdx.z * gridDim.y + blockIdx.y;
    }
    const int by = rowg % gridDim.y;
    const int bz = rowg / gridDim.y;

    const int zq = bz / p.zmod, zr = bz % p.zmod;
    const bf16* A  = p.A  + (long)zq * p.sA1 + (long)zr * p.sA2;
    const bf16* Bt = p.Bt + (long)zq * p.sB1 + (long)zr * p.sB2;
    const int row0 = by * BM, col0 = bx * 128;

    __shared__ __align__(16) bf16 shm[NBUF * (BM * 32) + NBUF * 4096];

    const int tid = threadIdx.x;
    const int l = tid & 63, w = tid >> 6;
    const int wr = w >> 1, wc = w & 1;

    f32x4 acc[MREP][4];
    #pragma unroll
    for (int m = 0; m < MREP; m++)
        #pragma unroll
        for (int n = 0; n < 4; n++)
            acc[m][n] = (f32x4){0.f, 0.f, 0.f, 0.f};

    const bf16* gA = A  + (long)(row0 + w * 16 + (l >> 2)) * p.lda + (l & 3) * 8;
    const bf16* gB = Bt + (long)(col0 + w * 16 + (l >> 2)) * p.ldb + (l & 3) * 8;

    auto STAGE_A = [&](int buf) {
        bf16* lA = shm + buf * ABUF;
        #pragma unroll
        for (int r = 0; r < BM / 64; r++)
            GLDS16(gA + (long)r * 64 * p.lda, lA + r * 2048 + w * 512);
        gA += 32;
    };
    auto STAGE_B = [&](int buf) {
        bf16* lB = shm + BBASE + buf * 4096;
        GLDS16(gB,               lB + w * 512);
        GLDS16(gB + 64 * p.ldb,  lB + 2048 + w * 512);
        gB += 32;
    };
    auto COMPUTE = [&](int buf) {
        const bf16* lA = shm + buf * ABUF;
        const bf16* lB = shm + BBASE + buf * 4096;
        bf16x8 aF[MREP], bF[4];
        #pragma unroll
        for (int n = 0; n < 4; n++)
            bF[n] = *(const bf16x8*)(lB + (wc * 64 + n * 16 + (l & 15)) * 32 + (l >> 4) * 8);
        #pragma unroll
        for (int m = 0; m < MREP; m++)
            aF[m] = *(const bf16x8*)(lA + (wr * WM + m * 16 + (l & 15)) * 32 + (l >> 4) * 8);
        #pragma unroll
        for (int m = 0; m < MREP; m++)
            #pragma unroll
            for (int n = 0; n < 4; n++)
                acc[m][n] = __builtin_amdgcn_mfma_f32_16x16x32_bf16(aF[m], bF[n], acc[m][n], 0, 0, 0);
    };

    const int nt = p.K >> 5;

    if constexpr (NBUF == 2) {
        // ---- 2-buffer, 2-barrier counted-vmcnt loop (R9-proven) ----
        STAGE_A(0); STAGE_B(0);
        int cur = 0;
        for (int t = 0; t < nt - 1; ++t) {
            STAGE_A(cur ^ 1); STAGE_B(cur ^ 1);
            if constexpr (BM == 256)
                asm volatile("s_waitcnt vmcnt(6)" ::: "memory");
            else
                asm volatile("s_waitcnt vmcnt(4)" ::: "memory");
            __builtin_amdgcn_sched_barrier(0);
            __builtin_amdgcn_s_barrier();
            COMPUTE(cur);
            __builtin_amdgcn_sched_barrier(0);
            __builtin_amdgcn_s_barrier();
            cur ^= 1;
        }
        asm volatile("s_waitcnt vmcnt(0)" ::: "memory");
        __builtin_amdgcn_sched_barrier(0);
        __builtin_amdgcn_s_barrier();
        COMPUTE(cur);
    } else {
        // ---- 3-buffer, 1-barrier, 2-phase interleaved loop (R17) ----
        STAGE_A(0); STAGE_B(0);
        STAGE_A(1); STAGE_B(1);
        int cb = 0, sb = 2;
        for (int t = 0; t < nt - 1; ++t) {
            if constexpr (BM == 256)
                asm volatile("s_waitcnt vmcnt(6)" ::: "memory");
            else
                asm volatile("s_waitcnt vmcnt(4)" ::: "memory");
            __builtin_amdgcn_sched_barrier(0);
            __builtin_amdgcn_s_barrier();
            __builtin_amdgcn_sched_barrier(0);

            const bf16* lA = shm + cb * ABUF;
            const bf16* lB = shm + BBASE + cb * 4096;
            const bool doStage = (t + 2 < nt);

            bf16x8 aF[MREP], bF[4];
            #pragma unroll
            for (int n = 0; n < 4; n++)
                bF[n] = *(const bf16x8*)(lB + (wc * 64 + n * 16 + (l & 15)) * 32 + (l >> 4) * 8);
            #pragma unroll
            for (int m = 0; m < HREP; m++)
                aF[m] = *(const bf16x8*)(lA + (wr * WM + m * 16 + (l & 15)) * 32 + (l >> 4) * 8);
            if (doStage) STAGE_A(sb);
            __builtin_amdgcn_s_setprio(1);
            #pragma unroll
            for (int m = 0; m < HREP; m++)
                #pragma unroll
                for (int n = 0; n < 4; n++)
                    acc[m][n] = __builtin_amdgcn_mfma_f32_16x16x32_bf16(aF[m], bF[n], acc[m][n], 0, 0, 0);
            __builtin_amdgcn_s_setprio(0);
            __builtin_amdgcn_s_barrier();
            __builtin_amdgcn_sched_barrier(0);

            #pragma unroll
            for (int m = HREP; m < MREP; m++)
                aF[m] = *(const bf16x8*)(lA + (wr * WM + m * 16 + (l & 15)) * 32 + (l >> 4) * 8);
            if (doStage) STAGE_B(sb);
            __builtin_amdgcn_s_setprio(1);
            #pragma unroll
            for (int m = HREP; m < MREP; m++)
                #pragma unroll
                for (int n = 0; n < 4; n++)
                    acc[m][n] = __builtin_amdgcn_mfma_f32_16x16x32_bf16(aF[m], bF[n], acc[m][n], 0, 0, 0);
            __builtin_amdgcn_s_setprio(0);

            cb = (cb == 2) ? 0 : cb + 1;
            sb = (sb == 2) ? 0 : sb + 1;
        }
        asm volatile("s_waitcnt vmcnt(0)" ::: "memory");
        __builtin_amdgcn_sched_barrier(0);
        __builtin_amdgcn_s_barrier();
        COMPUTE(cb);
    }

    const long cz = (long)zq * p.sC1 + (long)zr * p.sC2;
    const long rz = (long)zq * p.sR1 + (long)zr * p.sR2;
    #pragma unroll
    for (int m = 0; m < MREP; m++) {
        #pragma unroll
        for (int n = 0; n < 4; n++) {
            const int gcol = col0 + wc * 64 + n * 16 + (l & 15);
            if constexpr (EPI == E_QKV) {
                if (gcol >= 2560) {
                    const int c3 = gcol - 2560;
                    const int h_ = c3 >> 8, d_ = c3 & 255;
                    const int gr0 = row0 + wr * WM + m * 16 + (l >> 4) * 4;
                    const int b_ = gr0 >> 8, c0b = gr0 & 255;
                    const float bb = p.bias3[c3];
                    bf16 t4[4];
                    #pragma unroll
                    for (int j = 0; j < 4; j++) t4[j] = f2bf(acc[m][n][j] + bb);
                    *(uint2*)(p.outB3 + (((long)((b_ * H_ + h_) * 256 + d_)) << 8) + c0b) =
                        *(uint2*)t4;
                    continue;
                }
            }
            #pragma unroll
            for (int j = 0; j < 4; j++) {
                const int grow = row0 + wr * WM + m * 16 + (l >> 4) * 4 + j;
                const float v = acc[m][n][j];
                if constexpr (EPI == E_NODE) {
                    p.outB[cz + (long)grow * p.ldc + gcol] =
                        f2bf(v + p.bias[gcol] + p.res[rz + (long)grow * p.ldres + gcol]);
                } else if constexpr (EPI == E_HRES) {
                    p.outB[cz + (long)grow * p.ldc + gcol] =
                        f2bf(v + p.bias[gcol] + bf2f(p.resB[rz + (long)grow * p.ldres + gcol]));
                } else if constexpr (EPI == E_BF16) {
                    p.outB[cz + (long)grow * p.ldc + gcol] = f2bf(v);
                } else if constexpr (EPI == E_GELU) {
                    const float t = v + p.bias[gcol];
                    p.outB[cz + (long)grow * p.ldc + gcol] =
                        f2bf(0.5f * t * (1.0f + erff(t * 0.70710678f)));
                } else if constexpr (EPI == E_FFN2T) {
                    const float t = v + p.bias[gcol] +
                                    bf2f(p.resB[rz + (long)grow * p.ldres + gcol]);
                    const int b_ = grow >> 8, ci = grow & 255;
                    p.outB[(long)b_ * (1282 * 256) + (long)(gcol + 1) * 256 + ci] = f2bf(t);
                } else if constexpr (EPI == E_CONVBNR) {
                    const float t = v * p.rowscale[grow] + p.rowbias[grow];
                    p.outF[cz + (long)grow * p.ldc + gcol] = fmaxf(t, 0.0f);
                } else if constexpr (EPI == E_QKV) {
                    if (gcol < 1280) {
                        p.outB[(long)grow * L_ + gcol] = f2bf((v + p.bias[gcol]) * p.scale);
                    } else {
                        const int c2 = gcol - 1280;
                        p.outB2[(long)grow * L_ + c2] = f2bf(v + p.bias2[c2]);
                    }
                }
            }
        }
    }
}

// ---------------------------------------------------------------------------
extern "C" void kernel_launch(void* const* d_in, const int* in_sizes, int n_in,
                              void* d_out, int out_size, void* d_ws, size_t ws_size,
                              hipStream_t stream) {
    const float* x    = (const float*)d_in[0];
    const float* re_w = (const float*)d_in[1];
    const float* re_b = (const float*)d_in[2];
    const float* ln1g = (const float*)d_in[3];
    const float* ln1b = (const float*)d_in[4];
    const float* ln2g = (const float*)d_in[5];
    const float* ln2b = (const float*)d_in[6];
    const float* wq   = (const float*)d_in[7];
    const float* bq   = (const float*)d_in[8];
    const float* wk   = (const float*)d_in[9];
    const float* bk   = (const float*)d_in[10];
    const float* wv   = (const float*)d_in[11];
    const float* bv   = (const float*)d_in[12];
    const float* wo   = (const float*)d_in[13];
    const float* bo   = (const float*)d_in[14];
    const float* fw1  = (const float*)d_in[15];
    const float* fb1  = (const float*)d_in[16];
    const float* fw2  = (const float*)d_in[17];
    const float* fb2  = (const float*)d_in[18];
    const float* convw = (const float*)d_in[19];
    const float* bng  = (const float*)d_in[20];
    const float* bnb  = (const float*)d_in[21];
    const float* bnm  = (const float*)d_in[22];
    const float* bnv  = (const float*)d_in[23];
    float* out = (float*)d_out;

    // ---- workspace layout (total ~170 MB) ----
    char* ws = (char*)d_ws;
    const size_t SZ_WT     = (size_t)L_ * L_ * 2;          // 3,276,800
    const size_t SZ_ACT_BF = (size_t)BC_ * L_ * 2;         // 20,971,520
    const size_t SZ_H2T    = (size_t)B_ * 1282 * 256 * 2;  // 21,004,288
    const size_t SZ_S      = (size_t)160 * 256 * 256 * 4;  // 41,943,040

    size_t off = 0;
    bf16* Wt[7];
    for (int i = 0; i < 7; i++) { Wt[i] = (bf16*)(ws + off); off += SZ_WT; }  // contiguous!
    bf16* WconvT   = (bf16*)(ws + off); off += 393216;
    float* bnscale = (float*)(ws + off); off += 1024;
    float* bnbias  = (float*)(ws + off); off += 1024;
    bf16* RP  = (bf16*)(ws + off); off += SZ_ACT_BF;  // rank -> P -> y2
    bf16* Yb  = (bf16*)(ws + off); off += SZ_ACT_BF;  // y -> f1
    bf16* Qb  = (bf16*)(ws + off); off += SZ_ACT_BF;  // q -> attn O
    bf16* Kb  = (bf16*)(ws + off); off += SZ_H2T;     // k -> h2Tpad
    float* Sb = (float*)(ws + off); off += SZ_S;      // [unused 21MB][VT 21MB]
    bf16* nodeB = (bf16*)(ws + off); off += SZ_ACT_BF; // node -> h (bf16, in place)
    bf16* Sbf = (bf16*)Sb;                             // (kept for layout stability)
    bf16* VT  = Sbf + (size_t)160 * 65536;             // V^T, second half
    (void)in_sizes; (void)n_in; (void)out_size;

    // Diagnostic guard: if ws is too small, fail cleanly (absmax ~8.5, no fault)
    if (ws_size < off) return;

    // ---- weight prep ----
    WtArgs wa;
    wa.src[0] = re_w; wa.src[1] = wq; wa.src[2] = wk; wa.src[3] = wv;
    wa.src[4] = wo;  wa.src[5] = fw1; wa.src[6] = fw2;
    for (int i = 0; i < 7; i++) wa.dst[i] = Wt[i];
    transpose7<<<dim3(40, 40, 7), dim3(32, 8), 0, stream>>>(wa);
    prep_conv<<<dim3(768), 256, 0, stream>>>(convw, bng, bnb, bnm, bnv, WconvT, bnscale, bnbias);

    // ---- rank ----
    rank_kernel<<<dim3(BC_), 256, 0, stream>>>(x, RP);

    const dim3 gBig(L_ / 128, BC_ / 128, 1);      // (10, 64) — BM=128
    const dim3 gQKV(3840 / 128, BC_ / 256, 1);    // (30, 32) — BM=256
    const dim3 gAttn(2, 2, 160);                  // BM=128 (PV)
    const dim3 blk(256);

    // ---- node = bf16(x + rank @ re_w + re_b) ----
    {
        GemmP p{}; p.zmod = 1; p.K = L_;
        p.A = RP; p.lda = L_; p.Bt = Wt[0]; p.ldb = L_;
        p.outB = nodeB; p.ldc = L_; p.bias = re_b; p.res = x; p.ldres = L_;
        gemm_bt<E_NODE, 128, 3><<<gBig, blk, 0, stream>>>(p);
    }
    // ---- LN1 -> y ----
    ln_kernel<<<dim3(BC_), blk, 0, stream>>>(nodeB, ln1g, ln1b, Yb);
    // ---- Q (scaled) + K + V fused: BM=256, NBUF=2 (48KB -> 3 blocks/CU) ----
    {
        GemmP p{}; p.zmod = 1; p.K = L_;
        p.A = Yb; p.lda = L_; p.Bt = Wt[1]; p.ldb = L_;
        p.outB = Qb; p.outB2 = Kb; p.outB3 = VT;
        p.bias = bq; p.bias2 = bk; p.bias3 = bv; p.scale = 0.0625f;
        gemm_bt<E_QKV, 256, 2><<<gQKV, blk, 0, stream>>>(p);
    }
    // ---- fused S=QK^T + softmax -> P (into RP; rank is dead) ----
    attn_sfuse<<<dim3(2, 1, 160), blk, 0, stream>>>(Qb, Kb, RP);
    // ---- O = P V  (into Qb; q is dead) ----
    {
        GemmP p{}; p.zmod = H_; p.K = 256;
        p.A = RP;  p.lda = 256; p.sA1 = (long)H_ * 65536; p.sA2 = 65536;
        p.Bt = VT; p.ldb = 256; p.sB1 = (long)H_ * 65536; p.sB2 = 65536;
        p.outB = Qb; p.ldc = L_; p.sC1 = (long)C_ * L_; p.sC2 = 256;
        gemm_bt<E_BF16, 128, 3><<<gAttn, blk, 0, stream>>>(p);
    }
    // ---- h = bf16(node + O @ wo + bo)  (in place over nodeB) ----
    {
        GemmP p{}; p.zmod = 1; p.K = L_;
        p.A = Qb; p.lda = L_; p.Bt = Wt[4]; p.ldb = L_;
        p.outB = nodeB; p.ldc = L_; p.bias = bo; p.resB = nodeB; p.ldres = L_;
        gemm_bt<E_HRES, 128, 3><<<gBig, blk, 0, stream>>>(p);
    }
    // ---- LN2 -> y2 (RP; P is dead) ----
    ln_kernel<<<dim3(BC_), blk, 0, stream>>>(nodeB, ln2g, ln2b, RP);
    // ---- f1 = gelu(y2 @ w1 + b1) (Yb; y is dead) ----
    {
        GemmP p{}; p.zmod = 1; p.K = L_;
        p.A = RP; p.lda = L_; p.Bt = Wt[5]; p.ldb = L_;
        p.outB = Yb; p.ldc = L_; p.bias = fb1;
        gemm_bt<E_GELU, 128, 3><<<gBig, blk, 0, stream>>>(p);
    }
    // ---- h2 = h + f1 @ w2 + b2 -> transposed+padded (Kb; k is dead) ----
    zero_pads<<<dim3(64), blk, 0, stream>>>(Kb);
    {
        GemmP p{}; p.zmod = 1; p.K = L_;
        p.A = Yb; p.lda = L_; p.Bt = Wt[6]; p.ldb = L_;
        p.outB = Kb; p.bias = fb2; p.resB = nodeB; p.ldres = L_;
        gemm_bt<E_FFN2T, 128, 3><<<gBig, blk, 0, stream>>>(p);
    }
    // ---- conv: single fused K=768 GEMM + BN + ReLU ----
    {
        GemmP p{}; p.zmod = 1; p.K = 768;
        p.A = WconvT; p.lda = 768;                       // [co][t*256+ci]
        p.Bt = Kb; p.ldb = 256; p.sB1 = 1282 * 256;      // row lc reads h2T rows lc..lc+2
        p.outF = out; p.ldc = L_; p.sC1 = (long)C_ * L_;
        p.rowscale = bnscale; p.rowbias = bnbias;
        gemm_bt<E_CONVBNR, 128, 3><<<dim3(L_ / 128, 2, B_), blk, 0, stream>>>(p);
    }
}

// Round 20
// 513.149 us; speedup vs baseline: 1.0275x; 1.0275x over previous
//
#include <hip/hip_runtime.h>
#include <hip/hip_bf16.h>
#include <stdint.h>

// Problem constants
#define L_   1280
#define B_   32
#define C_   256
#define H_   5
#define D_   256
#define BC_  8192            // B_*C_
#define EPSV 1e-5f

typedef __attribute__((ext_vector_type(8))) short bf16x8;   // 8 bf16 (4 VGPRs)
typedef __attribute__((ext_vector_type(4))) float f32x4;    // 4 fp32 acc
typedef __hip_bfloat16 bf16;

__device__ __forceinline__ bf16 f2bf(float v) { return __float2bfloat16(v); }
__device__ __forceinline__ float bf2f(bf16 v) { return __bfloat162float(v); }

// async global->LDS, 16B per lane; LDS dest is wave-uniform base + lane*16
#define GLDS16(gptr, lptr)                                                        \
    __builtin_amdgcn_global_load_lds(                                             \
        (const __attribute__((address_space(1))) void*)(gptr),                    \
        (__attribute__((address_space(3))) void*)(lptr), 16, 0, 0)

// ---------------------------------------------------------------------------
// Weight prep: fp32 [K,N] -> bf16 [N,K] (transposed) for 7 LxL matrices
// ---------------------------------------------------------------------------
struct WtArgs { const float* src[7]; bf16* dst[7]; };

__global__ __launch_bounds__(256) void transpose7(WtArgs a) {
    const int mat = blockIdx.z;
    const float* src = a.src[mat];
    bf16* dst = a.dst[mat];
    __shared__ float tile[32][33];
    const int bx = blockIdx.x * 32;   // n base
    const int by = blockIdx.y * 32;   // k base
    const int tx = threadIdx.x, ty = threadIdx.y;
    #pragma unroll
    for (int r = ty; r < 32; r += 8)
        tile[r][tx] = src[(size_t)(by + r) * L_ + bx + tx];
    __syncthreads();
    #pragma unroll
    for (int r = ty; r < 32; r += 8)
        dst[(size_t)(bx + r) * L_ + by + tx] = f2bf(tile[tx][r]);
}

// conv weight pack: conv_w[co][ci][t] -> WT[co][t*256+ci]  (K=768 fused layout)
// plus BN scale/bias
__global__ __launch_bounds__(256) void prep_conv(const float* cw, const float* g, const float* b,
                                                 const float* m, const float* v,
                                                 bf16* WT, float* sc, float* bi) {
    const int i = blockIdx.x * 256 + threadIdx.x;
    if (i < 3 * 256 * 256) {
        const int co = i / 768;
        const int r = i - co * 768;
        const int t = r >> 8, ci = r & 255;
        WT[i] = f2bf(cw[(co * 256 + ci) * 3 + t]);
    }
    if (i < 256) {
        const float s = g[i] * rsqrtf(v[i] + EPSV);
        sc[i] = s;
        bi[i] = b[i] - m[i] * s;
    }
}

// ---------------------------------------------------------------------------
// Rank kernel (bucket-histogram; eq-before term dropped, < 2e-5 effect)
// ---------------------------------------------------------------------------
__global__ __launch_bounds__(256) void rank_kernel(const float* __restrict__ x, bf16* __restrict__ R) {
    __shared__ float vals[L_];
    __shared__ float sv[L_];
    __shared__ int hist[256];
    __shared__ int pfx[256];
    __shared__ int cur[256];
    const int row = blockIdx.x, tid = threadIdx.x;
    const float* src = x + (size_t)row * L_;
    for (int i = tid; i < L_; i += 256) vals[i] = src[i];
    hist[tid] = 0;
    __syncthreads();
    float myv[5]; int myb[5];
    #pragma unroll
    for (int ii = 0; ii < 5; ii++) {
        const float v = vals[tid + ii * 256];
        int bk = (int)((4.0f - v) * 32.0f);
        bk = bk < 0 ? 0 : (bk > 255 ? 255 : bk);
        myv[ii] = v; myb[ii] = bk;
        atomicAdd(&hist[bk], 1);
    }
    __syncthreads();
    pfx[tid] = hist[tid];
    __syncthreads();
    for (int off = 1; off < 256; off <<= 1) {
        int t = (tid >= off) ? pfx[tid - off] : 0;
        __syncthreads();
        pfx[tid] += t;
        __syncthreads();
    }
    cur[tid] = pfx[tid] - hist[tid];
    __syncthreads();
    #pragma unroll
    for (int ii = 0; ii < 5; ii++) {
        const int pos = atomicAdd(&cur[myb[ii]], 1);
        sv[pos] = myv[ii];
    }
    __syncthreads();
    #pragma unroll
    for (int ii = 0; ii < 5; ii++) {
        const int bk = myb[ii]; const float v = myv[ii];
        const int s = pfx[bk] - hist[bk], e = pfx[bk];
        int cg = s;
        for (int p = s; p < e; p++) cg += (sv[p] > v) ? 1 : 0;
        R[(size_t)row * L_ + tid + ii * 256] = f2bf((float)(L_ - cg) * (1.0f / L_));
    }
}

// ---------------------------------------------------------------------------
// LayerNorm over last dim (1280), bf16 in -> bf16 out
// ---------------------------------------------------------------------------
__global__ __launch_bounds__(256) void ln_kernel(const bf16* __restrict__ in,
                                                 const float* __restrict__ g,
                                                 const float* __restrict__ b,
                                                 bf16* __restrict__ out) {
    const int row = blockIdx.x, tid = threadIdx.x;
    const bf16* src = in + (size_t)row * L_;
    uint2 ra = ((const uint2*)src)[tid];
    bf16 a4[4]; *(uint2*)a4 = ra;
    const float a0 = bf2f(a4[0]), a1 = bf2f(a4[1]), a2 = bf2f(a4[2]), a3 = bf2f(a4[3]);
    float s = a0 + a1 + a2 + a3;
    float ss = a0 * a0 + a1 * a1 + a2 * a2 + a3 * a3;
    float b0 = 0, b1 = 0, b2 = 0, b3 = 0;
    if (tid < 64) {
        uint2 rb = ((const uint2*)src)[256 + tid];
        bf16 b4[4]; *(uint2*)b4 = rb;
        b0 = bf2f(b4[0]); b1 = bf2f(b4[1]); b2 = bf2f(b4[2]); b3 = bf2f(b4[3]);
        s += b0 + b1 + b2 + b3;
        ss += b0 * b0 + b1 * b1 + b2 * b2 + b3 * b3;
    }
    #pragma unroll
    for (int off = 32; off > 0; off >>= 1) {
        s += __shfl_down(s, off, 64);
        ss += __shfl_down(ss, off, 64);
    }
    __shared__ float rs[4], rss[4];
    __shared__ float mean_s, rstd_s;
    if ((tid & 63) == 0) { rs[tid >> 6] = s; rss[tid >> 6] = ss; }
    __syncthreads();
    if (tid == 0) {
        const float S = rs[0] + rs[1] + rs[2] + rs[3];
        const float SS = rss[0] + rss[1] + rss[2] + rss[3];
        const float m = S * (1.0f / L_);
        const float var = SS * (1.0f / L_) - m * m;
        mean_s = m; rstd_s = rsqrtf(var + EPSV);
    }
    __syncthreads();
    const float m = mean_s, r = rstd_s;
    {
        const int c = tid * 4;
        bf16 t4[4];
        t4[0] = f2bf((a0 - m) * r * g[c + 0] + b[c + 0]);
        t4[1] = f2bf((a1 - m) * r * g[c + 1] + b[c + 1]);
        t4[2] = f2bf((a2 - m) * r * g[c + 2] + b[c + 2]);
        t4[3] = f2bf((a3 - m) * r * g[c + 3] + b[c + 3]);
        *(uint2*)(out + (size_t)row * L_ + c) = *(uint2*)t4;
    }
    if (tid < 64) {
        const int c = 1024 + tid * 4;
        bf16 t4[4];
        t4[0] = f2bf((b0 - m) * r * g[c + 0] + b[c + 0]);
        t4[1] = f2bf((b1 - m) * r * g[c + 1] + b[c + 1]);
        t4[2] = f2bf((b2 - m) * r * g[c + 2] + b[c + 2]);
        t4[3] = f2bf((b3 - m) * r * g[c + 3] + b[c + 3]);
        *(uint2*)(out + (size_t)row * L_ + c) = *(uint2*)t4;
    }
}

// zero the two pad rows of h2Tpad [B][1282][256]
__global__ __launch_bounds__(256) void zero_pads(bf16* h2T) {
    const int i = blockIdx.x * 256 + threadIdx.x;   // 32*2*256 = 16384
    const int b = i >> 9;
    const int which = (i >> 8) & 1;
    const int ci = i & 255;
    const long row = which ? 1281 : 0;
    h2T[(long)b * (1282 * 256) + row * 256 + ci] = f2bf(0.0f);
}

// ---------------------------------------------------------------------------
// Fused S=QK^T + row-softmax -> P (bf16).  One block per (b,h,qtile128).
// ---------------------------------------------------------------------------
__global__ __launch_bounds__(256) void attn_sfuse(const bf16* __restrict__ Qb,
                                                  const bf16* __restrict__ Kb,
                                                  bf16* __restrict__ P) {
    const int z = blockIdx.z;                 // b*H + h
    const int b_ = z / H_, h_ = z % H_;
    const int row0 = blockIdx.x * 128;

    __shared__ __align__(16) bf16 shm[24576];

    const int tid = threadIdx.x;
    const int l = tid & 63, w = tid >> 6;
    const int wr = w >> 1, wc = w & 1;        // wave: rows wr*64, cols wc*128

    f32x4 acc[4][8];
    #pragma unroll
    for (int m = 0; m < 4; m++)
        #pragma unroll
        for (int n = 0; n < 8; n++)
            acc[m][n] = (f32x4){0.f, 0.f, 0.f, 0.f};

    const bf16* baseQ = Qb + (long)b_ * C_ * L_ + h_ * 256;
    const bf16* baseK = Kb + (long)b_ * C_ * L_ + h_ * 256;
    const bf16* gA = baseQ + (long)(row0 + w * 16 + (l >> 2)) * L_ + (l & 3) * 8;
    const bf16* gB = baseK + (long)(w * 16 + (l >> 2)) * L_ + (l & 3) * 8;

    auto STAGE = [&](int buf) {               // 6 loads/lane
        bf16* lA = shm + buf * 4096;
        bf16* lB = shm + 8192 + buf * 8192;
        GLDS16(gA,              lA + w * 512);
        GLDS16(gA + 64 * L_,    lA + 2048 + w * 512);
        #pragma unroll
        for (int c = 0; c < 4; c++)
            GLDS16(gB + (long)c * 64 * L_, lB + c * 2048 + w * 512);
        gA += 32; gB += 32;
    };
    auto COMPUTE = [&](int buf) {
        const bf16* lA = shm + buf * 4096;
        const bf16* lB = shm + 8192 + buf * 8192;
        bf16x8 aF[4], bF[8];
        #pragma unroll
        for (int n = 0; n < 8; n++)
            bF[n] = *(const bf16x8*)(lB + (wc * 128 + n * 16 + (l & 15)) * 32 + (l >> 4) * 8);
        #pragma unroll
        for (int m = 0; m < 4; m++)
            aF[m] = *(const bf16x8*)(lA + (wr * 64 + m * 16 + (l & 15)) * 32 + (l >> 4) * 8);
        #pragma unroll
        for (int m = 0; m < 4; m++)
            #pragma unroll
            for (int n = 0; n < 8; n++)
                acc[m][n] = __builtin_amdgcn_mfma_f32_16x16x32_bf16(aF[m], bF[n], acc[m][n], 0, 0, 0);
    };

    STAGE(0);
    int cur = 0;
    for (int t = 0; t < 7; ++t) {
        STAGE(cur ^ 1);
        asm volatile("s_waitcnt vmcnt(6)" ::: "memory");
        __builtin_amdgcn_sched_barrier(0);
        __builtin_amdgcn_s_barrier();
        COMPUTE(cur);
        __builtin_amdgcn_sched_barrier(0);
        __builtin_amdgcn_s_barrier();
        cur ^= 1;
    }
    asm volatile("s_waitcnt vmcnt(0)" ::: "memory");
    __builtin_amdgcn_sched_barrier(0);
    __builtin_amdgcn_s_barrier();
    COMPUTE(cur);

    // ---- row softmax ----
    float* red = (float*)shm;                 // [2][128], reused after barrier
    __syncthreads();                          // pipeline LDS reads complete
    const int lr = (l >> 4) * 4;              // local row base within 16-frag
    float rmax[4][4], rsum[4][4];
    #pragma unroll
    for (int m = 0; m < 4; m++)
        #pragma unroll
        for (int j = 0; j < 4; j++) {
            float v = acc[m][0][j];
            #pragma unroll
            for (int n = 1; n < 8; n++) v = fmaxf(v, acc[m][n][j]);
            #pragma unroll
            for (int mask = 1; mask < 16; mask <<= 1)
                v = fmaxf(v, __shfl_xor(v, mask, 64));
            rmax[m][j] = v;
        }
    if ((l & 15) == 0) {
        #pragma unroll
        for (int m = 0; m < 4; m++)
            #pragma unroll
            for (int j = 0; j < 4; j++)
                red[wc * 128 + wr * 64 + m * 16 + lr + j] = rmax[m][j];
    }
    __syncthreads();
    #pragma unroll
    for (int m = 0; m < 4; m++)
        #pragma unroll
        for (int j = 0; j < 4; j++)
            rmax[m][j] = fmaxf(rmax[m][j], red[(wc ^ 1) * 128 + wr * 64 + m * 16 + lr + j]);
    __syncthreads();                          // before red reuse for sums
    #pragma unroll
    for (int m = 0; m < 4; m++)
        #pragma unroll
        for (int j = 0; j < 4; j++) {
            float s = 0.f;
            #pragma unroll
            for (int n = 0; n < 8; n++) {
                const float e = expf(acc[m][n][j] - rmax[m][j]);
                acc[m][n][j] = e;
                s += e;
            }
            #pragma unroll
            for (int mask = 1; mask < 16; mask <<= 1)
                s += __shfl_xor(s, mask, 64);
            rsum[m][j] = s;
        }
    if ((l & 15) == 0) {
        #pragma unroll
        for (int m = 0; m < 4; m++)
            #pragma unroll
            for (int j = 0; j < 4; j++)
                red[wc * 128 + wr * 64 + m * 16 + lr + j] = rsum[m][j];
    }
    __syncthreads();
    #pragma unroll
    for (int m = 0; m < 4; m++)
        #pragma unroll
        for (int j = 0; j < 4; j++)
            rsum[m][j] += red[(wc ^ 1) * 128 + wr * 64 + m * 16 + lr + j];

    // ---- store P ----
    bf16* dstP = P + (long)z * 65536;
    #pragma unroll
    for (int m = 0; m < 4; m++)
        #pragma unroll
        for (int j = 0; j < 4; j++) {
            const int grow = row0 + wr * 64 + m * 16 + lr + j;
            const float rinv = 1.0f / rsum[m][j];
            #pragma unroll
            for (int n = 0; n < 8; n++) {
                const int gcol = wc * 128 + n * 16 + (l & 15);
                dstP[(long)grow * 256 + gcol] = f2bf(acc[m][n][j] * rinv);
            }
        }
}

// ---------------------------------------------------------------------------
// Generic batched GEMM: templated BM (128/256) x 128 cols, BK=32, 4 waves 2x2.
// 3-buffer rotation, counted vmcnt, 2-phase interleaved K-step + setprio
// (R17/R18-proven). XCD chunking with row-fastest order (B-tile L2 reuse).
// ---------------------------------------------------------------------------
struct GemmP {
    const bf16* A;  long lda, sA1, sA2;
    const bf16* Bt; long ldb, sB1, sB2;
    int zmod;
    int K;
    float* outF; bf16* outB; bf16* outB2; bf16* outB3; long ldc, sC1, sC2;
    const float* bias; const float* bias2; const float* bias3;
    const float* res; const bf16* resB; long ldres, sR1, sR2;
    const float* rowscale; const float* rowbias;
    float scale;
};

constexpr int E_NODE = 0;
constexpr int E_HRES = 1;
constexpr int E_BF16 = 5;
constexpr int E_GELU = 6;
constexpr int E_FFN2T = 7;
constexpr int E_CONVBNR = 8;
constexpr int E_QKV = 9;

template <int EPI, int BM>
__global__ __launch_bounds__(256) void gemm_bt(GemmP p) {
    constexpr int MREP  = BM / 32;
    constexpr int HREP  = MREP / 2;
    constexpr int WM    = BM / 2;
    constexpr int ABUF  = BM * 32;
    constexpr int BBASE = 3 * ABUF;

    const int nwg  = gridDim.x * gridDim.y * gridDim.z;
    const int orig = (blockIdx.z * gridDim.y + blockIdx.y) * gridDim.x + blockIdx.x;
    int bx, rowg;
    if ((nwg & 7) == 0) {
        const int chunk = nwg >> 3;
        const int xcd = orig & 7, pos = orig >> 3;
        const int rpc = chunk / gridDim.x;
        if (rpc * gridDim.x == chunk) {
            bx   = pos / rpc;
            rowg = xcd * rpc + (pos - bx * rpc);
        } else {
            const int wgid = xcd * chunk + pos;
            bx = wgid % gridDim.x; rowg = wgid / gridDim.x;
        }
    } else {
        bx = blockIdx.x; rowg = blockIdx.z * gridDim.y + blockIdx.y;
    }
    const int by = rowg % gridDim.y;
    const int bz = rowg / gridDim.y;

    const int zq = bz / p.zmod, zr = bz % p.zmod;
    const bf16* A  = p.A  + (long)zq * p.sA1 + (long)zr * p.sA2;
    const bf16* Bt = p.Bt + (long)zq * p.sB1 + (long)zr * p.sB2;
    const int row0 = by * BM, col0 = bx * 128;

    __shared__ __align__(16) bf16 shm[3 * (BM * 32) + 12288];

    const int tid = threadIdx.x;
    const int l = tid & 63, w = tid >> 6;
    const int wr = w >> 1, wc = w & 1;

    f32x4 acc[MREP][4];
    #pragma unroll
    for (int m = 0; m < MREP; m++)
        #pragma unroll
        for (int n = 0; n < 4; n++)
            acc[m][n] = (f32x4){0.f, 0.f, 0.f, 0.f};

    const bf16* gA = A  + (long)(row0 + w * 16 + (l >> 2)) * p.lda + (l & 3) * 8;
    const bf16* gB = Bt + (long)(col0 + w * 16 + (l >> 2)) * p.ldb + (l & 3) * 8;

    auto STAGE_A = [&](int buf) {
        bf16* lA = shm + buf * ABUF;
        #pragma unroll
        for (int r = 0; r < BM / 64; r++)
            GLDS16(gA + (long)r * 64 * p.lda, lA + r * 2048 + w * 512);
        gA += 32;
    };
    auto STAGE_B = [&](int buf) {
        bf16* lB = shm + BBASE + buf * 4096;
        GLDS16(gB,               lB + w * 512);
        GLDS16(gB + 64 * p.ldb,  lB + 2048 + w * 512);
        gB += 32;
    };

    const int nt = p.K >> 5;
    STAGE_A(0); STAGE_B(0);
    STAGE_A(1); STAGE_B(1);
    int cb = 0, sb = 2;
    for (int t = 0; t < nt - 1; ++t) {
        if constexpr (BM == 256)
            asm volatile("s_waitcnt vmcnt(6)" ::: "memory");
        else
            asm volatile("s_waitcnt vmcnt(4)" ::: "memory");
        __builtin_amdgcn_sched_barrier(0);
        __builtin_amdgcn_s_barrier();
        __builtin_amdgcn_sched_barrier(0);

        const bf16* lA = shm + cb * ABUF;
        const bf16* lB = shm + BBASE + cb * 4096;
        const bool doStage = (t + 2 < nt);

        bf16x8 aF[MREP], bF[4];
        #pragma unroll
        for (int n = 0; n < 4; n++)
            bF[n] = *(const bf16x8*)(lB + (wc * 64 + n * 16 + (l & 15)) * 32 + (l >> 4) * 8);
        #pragma unroll
        for (int m = 0; m < HREP; m++)
            aF[m] = *(const bf16x8*)(lA + (wr * WM + m * 16 + (l & 15)) * 32 + (l >> 4) * 8);
        if (doStage) STAGE_A(sb);
        __builtin_amdgcn_s_setprio(1);
        #pragma unroll
        for (int m = 0; m < HREP; m++)
            #pragma unroll
            for (int n = 0; n < 4; n++)
                acc[m][n] = __builtin_amdgcn_mfma_f32_16x16x32_bf16(aF[m], bF[n], acc[m][n], 0, 0, 0);
        __builtin_amdgcn_s_setprio(0);
        __builtin_amdgcn_s_barrier();
        __builtin_amdgcn_sched_barrier(0);

        #pragma unroll
        for (int m = HREP; m < MREP; m++)
            aF[m] = *(const bf16x8*)(lA + (wr * WM + m * 16 + (l & 15)) * 32 + (l >> 4) * 8);
        if (doStage) STAGE_B(sb);
        __builtin_amdgcn_s_setprio(1);
        #pragma unroll
        for (int m = HREP; m < MREP; m++)
            #pragma unroll
            for (int n = 0; n < 4; n++)
                acc[m][n] = __builtin_amdgcn_mfma_f32_16x16x32_bf16(aF[m], bF[n], acc[m][n], 0, 0, 0);
        __builtin_amdgcn_s_setprio(0);

        cb = (cb == 2) ? 0 : cb + 1;
        sb = (sb == 2) ? 0 : sb + 1;
    }
    asm volatile("s_waitcnt vmcnt(0)" ::: "memory");
    __builtin_amdgcn_sched_barrier(0);
    __builtin_amdgcn_s_barrier();
    {
        const bf16* lA = shm + cb * ABUF;
        const bf16* lB = shm + BBASE + cb * 4096;
        bf16x8 aF[MREP], bF[4];
        #pragma unroll
        for (int n = 0; n < 4; n++)
            bF[n] = *(const bf16x8*)(lB + (wc * 64 + n * 16 + (l & 15)) * 32 + (l >> 4) * 8);
        #pragma unroll
        for (int m = 0; m < MREP; m++)
            aF[m] = *(const bf16x8*)(lA + (wr * WM + m * 16 + (l & 15)) * 32 + (l >> 4) * 8);
        #pragma unroll
        for (int m = 0; m < MREP; m++)
            #pragma unroll
            for (int n = 0; n < 4; n++)
                acc[m][n] = __builtin_amdgcn_mfma_f32_16x16x32_bf16(aF[m], bF[n], acc[m][n], 0, 0, 0);
    }

    const long cz = (long)zq * p.sC1 + (long)zr * p.sC2;
    const long rz = (long)zq * p.sR1 + (long)zr * p.sR2;
    #pragma unroll
    for (int m = 0; m < MREP; m++) {
        #pragma unroll
        for (int n = 0; n < 4; n++) {
            const int gcol = col0 + wc * 64 + n * 16 + (l & 15);
            if constexpr (EPI == E_QKV) {
                if (gcol >= 2560) {
                    const int c3 = gcol - 2560;
                    const int h_ = c3 >> 8, d_ = c3 & 255;
                    const int gr0 = row0 + wr * WM + m * 16 + (l >> 4) * 4;
                    const int b_ = gr0 >> 8, c0b = gr0 & 255;
                    const float bb = p.bias3[c3];
                    bf16 t4[4];
                    #pragma unroll
                    for (int j = 0; j < 4; j++) t4[j] = f2bf(acc[m][n][j] + bb);
                    *(uint2*)(p.outB3 + (((long)((b_ * H_ + h_) * 256 + d_)) << 8) + c0b) =
                        *(uint2*)t4;
                    continue;
                }
            }
            #pragma unroll
            for (int j = 0; j < 4; j++) {
                const int grow = row0 + wr * WM + m * 16 + (l >> 4) * 4 + j;
                const float v = acc[m][n][j];
                if constexpr (EPI == E_NODE) {
                    p.outB[cz + (long)grow * p.ldc + gcol] =
                        f2bf(v + p.bias[gcol] + p.res[rz + (long)grow * p.ldres + gcol]);
                } else if constexpr (EPI == E_HRES) {
                    p.outB[cz + (long)grow * p.ldc + gcol] =
                        f2bf(v + p.bias[gcol] + bf2f(p.resB[rz + (long)grow * p.ldres + gcol]));
                } else if constexpr (EPI == E_BF16) {
                    p.outB[cz + (long)grow * p.ldc + gcol] = f2bf(v);
                } else if constexpr (EPI == E_GELU) {
                    const float t = v + p.bias[gcol];
                    p.outB[cz + (long)grow * p.ldc + gcol] =
                        f2bf(0.5f * t * (1.0f + erff(t * 0.70710678f)));
                } else if constexpr (EPI == E_FFN2T) {
                    const float t = v + p.bias[gcol] +
                                    bf2f(p.resB[rz + (long)grow * p.ldres + gcol]);
                    const int b_ = grow >> 8, ci = grow & 255;
                    p.outB[(long)b_ * (1282 * 256) + (long)(gcol + 1) * 256 + ci] = f2bf(t);
                } else if constexpr (EPI == E_CONVBNR) {
                    const float t = v * p.rowscale[grow] + p.rowbias[grow];
                    p.outF[cz + (long)grow * p.ldc + gcol] = fmaxf(t, 0.0f);
                } else if constexpr (EPI == E_QKV) {
                    if (gcol < 1280) {
                        p.outB[(long)grow * L_ + gcol] = f2bf((v + p.bias[gcol]) * p.scale);
                    } else {
                        const int c2 = gcol - 1280;
                        p.outB2[(long)grow * L_ + c2] = f2bf(v + p.bias2[c2]);
                    }
                }
            }
        }
    }
}

// ---------------------------------------------------------------------------
extern "C" void kernel_launch(void* const* d_in, const int* in_sizes, int n_in,
                              void* d_out, int out_size, void* d_ws, size_t ws_size,
                              hipStream_t stream) {
    const float* x    = (const float*)d_in[0];
    const float* re_w = (const float*)d_in[1];
    const float* re_b = (const float*)d_in[2];
    const float* ln1g = (const float*)d_in[3];
    const float* ln1b = (const float*)d_in[4];
    const float* ln2g = (const float*)d_in[5];
    const float* ln2b = (const float*)d_in[6];
    const float* wq   = (const float*)d_in[7];
    const float* bq   = (const float*)d_in[8];
    const float* wk   = (const float*)d_in[9];
    const float* bk   = (const float*)d_in[10];
    const float* wv   = (const float*)d_in[11];
    const float* bv   = (const float*)d_in[12];
    const float* wo   = (const float*)d_in[13];
    const float* bo   = (const float*)d_in[14];
    const float* fw1  = (const float*)d_in[15];
    const float* fb1  = (const float*)d_in[16];
    const float* fw2  = (const float*)d_in[17];
    const float* fb2  = (const float*)d_in[18];
    const float* convw = (const float*)d_in[19];
    const float* bng  = (const float*)d_in[20];
    const float* bnb  = (const float*)d_in[21];
    const float* bnm  = (const float*)d_in[22];
    const float* bnv  = (const float*)d_in[23];
    float* out = (float*)d_out;

    // ---- workspace layout (total ~170 MB) ----
    char* ws = (char*)d_ws;
    const size_t SZ_WT     = (size_t)L_ * L_ * 2;          // 3,276,800
    const size_t SZ_ACT_BF = (size_t)BC_ * L_ * 2;         // 20,971,520
    const size_t SZ_H2T    = (size_t)B_ * 1282 * 256 * 2;  // 21,004,288
    const size_t SZ_S      = (size_t)160 * 256 * 256 * 4;  // 41,943,040

    size_t off = 0;
    bf16* Wt[7];
    for (int i = 0; i < 7; i++) { Wt[i] = (bf16*)(ws + off); off += SZ_WT; }  // contiguous!
    bf16* WconvT   = (bf16*)(ws + off); off += 393216;
    float* bnscale = (float*)(ws + off); off += 1024;
    float* bnbias  = (float*)(ws + off); off += 1024;
    bf16* RP  = (bf16*)(ws + off); off += SZ_ACT_BF;  // rank -> P -> y2
    bf16* Yb  = (bf16*)(ws + off); off += SZ_ACT_BF;  // y -> f1
    bf16* Qb  = (bf16*)(ws + off); off += SZ_ACT_BF;  // q -> attn O
    bf16* Kb  = (bf16*)(ws + off); off += SZ_H2T;     // k -> h2Tpad
    float* Sb = (float*)(ws + off); off += SZ_S;      // [unused 21MB][VT 21MB]
    bf16* nodeB = (bf16*)(ws + off); off += SZ_ACT_BF; // node -> h (bf16, in place)
    bf16* Sbf = (bf16*)Sb;                             // (kept for layout stability)
    bf16* VT  = Sbf + (size_t)160 * 65536;             // V^T, second half
    (void)in_sizes; (void)n_in; (void)out_size;

    // Diagnostic guard: if ws is too small, fail cleanly (absmax ~8.5, no fault)
    if (ws_size < off) return;

    // ---- weight prep ----
    WtArgs wa;
    wa.src[0] = re_w; wa.src[1] = wq; wa.src[2] = wk; wa.src[3] = wv;
    wa.src[4] = wo;  wa.src[5] = fw1; wa.src[6] = fw2;
    for (int i = 0; i < 7; i++) wa.dst[i] = Wt[i];
    transpose7<<<dim3(40, 40, 7), dim3(32, 8), 0, stream>>>(wa);
    prep_conv<<<dim3(768), 256, 0, stream>>>(convw, bng, bnb, bnm, bnv, WconvT, bnscale, bnbias);

    // ---- rank ----
    rank_kernel<<<dim3(BC_), 256, 0, stream>>>(x, RP);

    const dim3 gBig(L_ / 128, BC_ / 128, 1);      // (10, 64) — BM=128
    const dim3 gQKV(3840 / 128, BC_ / 256, 1);    // (30, 32) — BM=256
    const dim3 gAttn(2, 2, 160);                  // BM=128 (PV)
    const dim3 blk(256);

    // ---- node = bf16(x + rank @ re_w + re_b) ----
    {
        GemmP p{}; p.zmod = 1; p.K = L_;
        p.A = RP; p.lda = L_; p.Bt = Wt[0]; p.ldb = L_;
        p.outB = nodeB; p.ldc = L_; p.bias = re_b; p.res = x; p.ldres = L_;
        gemm_bt<E_NODE, 128><<<gBig, blk, 0, stream>>>(p);
    }
    // ---- LN1 -> y ----
    ln_kernel<<<dim3(BC_), blk, 0, stream>>>(nodeB, ln1g, ln1b, Yb);
    // ---- Q (scaled) + K + V fused: Bt = Wt[1]||Wt[2]||Wt[3]; BM=256 ----
    {
        GemmP p{}; p.zmod = 1; p.K = L_;
        p.A = Yb; p.lda = L_; p.Bt = Wt[1]; p.ldb = L_;
        p.outB = Qb; p.outB2 = Kb; p.outB3 = VT;
        p.bias = bq; p.bias2 = bk; p.bias3 = bv; p.scale = 0.0625f;
        gemm_bt<E_QKV, 256><<<gQKV, blk, 0, stream>>>(p);
    }
    // ---- fused S=QK^T + softmax -> P (into RP; rank is dead) ----
    attn_sfuse<<<dim3(2, 1, 160), blk, 0, stream>>>(Qb, Kb, RP);
    // ---- O = P V  (into Qb; q is dead) ----
    {
        GemmP p{}; p.zmod = H_; p.K = 256;
        p.A = RP;  p.lda = 256; p.sA1 = (long)H_ * 65536; p.sA2 = 65536;
        p.Bt = VT; p.ldb = 256; p.sB1 = (long)H_ * 65536; p.sB2 = 65536;
        p.outB = Qb; p.ldc = L_; p.sC1 = (long)C_ * L_; p.sC2 = 256;
        gemm_bt<E_BF16, 128><<<gAttn, blk, 0, stream>>>(p);
    }
    // ---- h = bf16(node + O @ wo + bo)  (in place over nodeB) ----
    {
        GemmP p{}; p.zmod = 1; p.K = L_;
        p.A = Qb; p.lda = L_; p.Bt = Wt[4]; p.ldb = L_;
        p.outB = nodeB; p.ldc = L_; p.bias = bo; p.resB = nodeB; p.ldres = L_;
        gemm_bt<E_HRES, 128><<<gBig, blk, 0, stream>>>(p);
    }
    // ---- LN2 -> y2 (RP; P is dead) ----
    ln_kernel<<<dim3(BC_), blk, 0, stream>>>(nodeB, ln2g, ln2b, RP);
    // ---- f1 = gelu(y2 @ w1 + b1) (Yb; y is dead) ----
    {
        GemmP p{}; p.zmod = 1; p.K = L_;
        p.A = RP; p.lda = L_; p.Bt = Wt[5]; p.ldb = L_;
        p.outB = Yb; p.ldc = L_; p.bias = fb1;
        gemm_bt<E_GELU, 128><<<gBig, blk, 0, stream>>>(p);
    }
    // ---- h2 = h + f1 @ w2 + b2 -> transposed+padded (Kb; k is dead) ----
    zero_pads<<<dim3(64), blk, 0, stream>>>(Kb);
    {
        GemmP p{}; p.zmod = 1; p.K = L_;
        p.A = Yb; p.lda = L_; p.Bt = Wt[6]; p.ldb = L_;
        p.outB = Kb; p.bias = fb2; p.resB = nodeB; p.ldres = L_;
        gemm_bt<E_FFN2T, 128><<<gBig, blk, 0, stream>>>(p);
    }
    // ---- conv: single fused K=768 GEMM + BN + ReLU ----
    {
        GemmP p{}; p.zmod = 1; p.K = 768;
        p.A = WconvT; p.lda = 768;                       // [co][t*256+ci]
        p.Bt = Kb; p.ldb = 256; p.sB1 = 1282 * 256;      // row lc reads h2T rows lc..lc+2
        p.outF = out; p.ldc = L_; p.sC1 = (long)C_ * L_;
        p.rowscale = bnscale; p.rowbias = bnbias;
        gemm_bt<E_CONVBNR, 128><<<dim3(L_ / 128, 2, B_), blk, 0, stream>>>(p);
    }
}